// Round 1
// baseline (297.042 us; speedup 1.0000x reference)
//
#include <hip/hip_runtime.h>
#include <hip/hip_fp16.h>

typedef _Float16 f16x8 __attribute__((ext_vector_type(8)));
typedef float f32x16 __attribute__((ext_vector_type(16)));

#define LOG2E 1.44269504088896340736f

static __device__ __forceinline__ f32x16 zero16() {
  f32x16 z;
#pragma unroll
  for (int i = 0; i < 16; ++i) z[i] = 0.0f;
  return z;
}

static __device__ __forceinline__ unsigned pkh(float a, float b) {
  union { _Float16 h[2]; unsigned u; } t;
  t.h[0] = (_Float16)a; t.h[1] = (_Float16)b;
  return t.u;
}

// exchange: a = (hi ? partner's y : own x), c = (hi ? own y : partner's x)
static __device__ __forceinline__ void swap32(unsigned x, unsigned y, int hi,
                                              unsigned& a, unsigned& c) {
  unsigned py = (unsigned)__shfl_xor((int)y, 32);
  unsigned px = (unsigned)__shfl_xor((int)x, 32);
  a = hi ? py : x;
  c = hi ? y : px;
}

// ---------------------------------------------------------------------------
// GEMM: out = A @ W^T.  A: [4096 x 512], W: [512 x 512] f32 (converted to f16
// while staging).  Tile 64(M) x 128(N), BK=64, 256 threads (4 waves, 2x2).
// MODE 0: A f32, out f16 row-major [4096][512]
// MODE 1: A f32, out scattered as v_t[b][h][d][s] f16
// MODE 2: A f16 (embeds), out f32 row-major (d_out)
// ---------------------------------------------------------------------------
template <int MODE>
__global__ __launch_bounds__(256) void gemm_kernel(const void* __restrict__ Ap,
                                                   const float* __restrict__ W,
                                                   void* __restrict__ outp) {
  __shared__ char smem[8192 + 16384];  // As [64][64] f16, Ws [128][64] f16
  const int tid = threadIdx.x;
  const int l = tid & 63, lo = l & 31, hi = l >> 5;
  const int w = tid >> 6, wm = w >> 1, wn = w & 1;
  const int m0 = blockIdx.y * 64, n0 = blockIdx.x * 128;

  f32x16 acc[2];
  acc[0] = zero16();
  acc[1] = zero16();

  for (int kb = 0; kb < 8; ++kb) {
    // stage A -> As (f16, swizzled)
    if constexpr (MODE == 2) {
      const _Float16* A = (const _Float16*)Ap;
#pragma unroll
      for (int i = 0; i < 2; ++i) {
        int idx = tid + 256 * i; int r = idx >> 3, c8 = idx & 7;
        f16x8 v = *(const f16x8*)(A + (size_t)(m0 + r) * 512 + kb * 64 + c8 * 8);
        *(f16x8*)(smem + ((r * 128 + c8 * 16) ^ ((r & 7) << 4))) = v;
      }
    } else {
      const float* A = (const float*)Ap;
#pragma unroll
      for (int i = 0; i < 4; ++i) {
        int idx = tid + 256 * i; int r = idx >> 4, c4 = idx & 15;
        float4 v = *(const float4*)(A + (size_t)(m0 + r) * 512 + kb * 64 + c4 * 4);
        uint2 uu; uu.x = pkh(v.x, v.y); uu.y = pkh(v.z, v.w);
        *(uint2*)(smem + ((r * 128 + c4 * 8) ^ ((r & 7) << 4))) = uu;
      }
    }
    // stage W -> Ws
#pragma unroll
    for (int i = 0; i < 8; ++i) {
      int idx = tid + 256 * i; int r = idx >> 4, c4 = idx & 15;
      float4 v = *(const float4*)(W + (size_t)(n0 + r) * 512 + kb * 64 + c4 * 4);
      uint2 uu; uu.x = pkh(v.x, v.y); uu.y = pkh(v.z, v.w);
      *(uint2*)(smem + 8192 + ((r * 128 + c4 * 8) ^ ((r & 7) << 4))) = uu;
    }
    __syncthreads();
#pragma unroll
    for (int ks = 0; ks < 4; ++ks) {
      int ra = wm * 32 + lo;
      f16x8 a0 = *(const f16x8*)(smem + ((ra * 128 + ks * 32 + hi * 16) ^ ((ra & 7) << 4)));
      int rb0 = wn * 64 + lo, rb1 = rb0 + 32;
      f16x8 b0 = *(const f16x8*)(smem + 8192 + ((rb0 * 128 + ks * 32 + hi * 16) ^ ((rb0 & 7) << 4)));
      f16x8 b1 = *(const f16x8*)(smem + 8192 + ((rb1 * 128 + ks * 32 + hi * 16) ^ ((rb1 & 7) << 4)));
      acc[0] = __builtin_amdgcn_mfma_f32_32x32x16_f16(a0, b0, acc[0], 0, 0, 0);
      acc[1] = __builtin_amdgcn_mfma_f32_32x32x16_f16(a0, b1, acc[1], 0, 0, 0);
    }
    __syncthreads();
  }

  if constexpr (MODE == 0) {
    _Float16* out = (_Float16*)outp;
#pragma unroll
    for (int nt = 0; nt < 2; ++nt) {
      int n = n0 + wn * 64 + nt * 32 + lo;
#pragma unroll
      for (int r = 0; r < 16; ++r) {
        int m = m0 + wm * 32 + (r & 3) + 8 * ((r >> 2) & 3) + 4 * hi;
        out[(size_t)m * 512 + n] = (_Float16)acc[nt][r];
      }
    }
  } else if constexpr (MODE == 1) {
    _Float16* vt = (_Float16*)outp;
#pragma unroll
    for (int nt = 0; nt < 2; ++nt) {
      int n = n0 + wn * 64 + nt * 32 + lo;
      int hh = n >> 6, d = n & 63;
#pragma unroll
      for (int a = 0; a < 4; ++a) {
        int m = m0 + wm * 32 + 8 * a + 4 * hi;
        int b_ = m >> 11, s = m & 2047;
        uint2 uu;
        uu.x = pkh(acc[nt][4 * a + 0], acc[nt][4 * a + 1]);
        uu.y = pkh(acc[nt][4 * a + 2], acc[nt][4 * a + 3]);
        *(uint2*)(vt + (size_t)((b_ * 8 + hh) * 64 + d) * 2048 + s) = uu;
      }
    }
  } else {
    float* out = (float*)outp;
#pragma unroll
    for (int nt = 0; nt < 2; ++nt) {
      int n = n0 + wn * 64 + nt * 32 + lo;
#pragma unroll
      for (int r = 0; r < 16; ++r) {
        int m = m0 + wm * 32 + (r & 3) + 8 * ((r >> 2) & 3) + 4 * hi;
        out[(size_t)m * 512 + n] = acc[nt][r];
      }
    }
  }
}

// ---------------------------------------------------------------------------
// RoPE over the full 512-dim projected row (pre-split_heads, as in reference).
// grid (4096, 2): x = row, y = tensor (0=q, 1=k). 256 threads = 256 pairs.
// ---------------------------------------------------------------------------
__global__ __launch_bounds__(256) void rope_kernel(const _Float16* __restrict__ qp,
                                                   const _Float16* __restrict__ kp,
                                                   _Float16* __restrict__ qrr,
                                                   _Float16* __restrict__ krr) {
  const int row = blockIdx.x;
  const _Float16* src = blockIdx.y ? kp : qp;
  _Float16* dst = blockIdx.y ? krr : qrr;
  const int i = threadIdx.x;
  const int pos = row & 2047;
  union { unsigned u; _Float16 h[2]; } t;
  t.u = *(const unsigned*)(src + (size_t)row * 512 + 2 * i);
  float pe = (float)t.h[0], po = (float)t.h[1];
  // freq_i = 10000^(-i/256) = exp2(-i * log2(10000)/256)
  float fr = exp2f(-(float)i * 0.05190512648261504f);
  float ang = (float)pos * fr;
  float sn, cs;
  sincosf(ang, &sn, &cs);
  dst[(size_t)row * 512 + i] = (_Float16)(pe * cs - po * sn);
  dst[(size_t)row * 512 + 256 + i] = (_Float16)(po * cs + pe * sn);
}

// ---------------------------------------------------------------------------
// Reduce attn_mask to a nonzero flag (fast-path detector; zeros in harness).
// ---------------------------------------------------------------------------
__global__ __launch_bounds__(256) void mask_scan(const float* __restrict__ mask,
                                                 int* __restrict__ flag) {
  const int n4 = 2 * 2048 * 2048 / 4;
  bool nz = false;
  for (int i = blockIdx.x * 256 + threadIdx.x; i < n4; i += gridDim.x * 256) {
    float4 v = ((const float4*)mask)[i];
    nz |= (v.x != 0.f) || (v.y != 0.f) || (v.z != 0.f) || (v.w != 0.f);
  }
  if (__any(nz) && (threadIdx.x & 63) == 0) atomicOr(flag, 1);
}

// ---------------------------------------------------------------------------
// Attention. grid (32 q-tiles, 16 bh), 128 threads (2 waves, 32 q-rows each).
// Pass 1: S^T = mfma(K,Q) -> lane-local sum of exp2(logit*C).
// Pass 2: recompute S^T, normalize, LDS-transpose -> coalesced score stores,
//         PV via shfl-reassembled P^T fragments into mfma(V^T, P^T).
// ---------------------------------------------------------------------------
__global__ __launch_bounds__(128) void attn_kernel(
    const _Float16* __restrict__ qr, const _Float16* __restrict__ kr,
    const _Float16* __restrict__ vt, const float* __restrict__ mask,
    const int* __restrict__ flagp, float* __restrict__ scores,
    _Float16* __restrict__ embeds) {
  __shared__ char smem[49152];
  // [0,8192)      Qs [64][64] f16,  swz ((r&7)<<4)
  // [8192,24576)  Ks [128][64] f16, swz ((r&7)<<4)
  // [24576,40960) Vs [64][128] f16 (V^T), swz ((d&7)<<4)
  // [40960,49152) per-wave p-transpose [32][32] f32, swz col^row
  const int tid = threadIdx.x;
  const int w = tid >> 6, l = tid & 63, lo = l & 31, hi = l >> 5;
  const int bh = blockIdx.y, b = bh >> 3, h = bh & 7;
  const int q0 = blockIdx.x * 64;
  const int mflag = *flagp;
  const float C = 0.125f * LOG2E;
  const int qw = q0 + w * 32 + lo;  // this lane's q column (S^T orientation)

  // stage Q tile
#pragma unroll
  for (int i = 0; i < 4; ++i) {
    int idx = tid + 128 * i; int r = idx >> 3, c8 = idx & 7;
    f16x8 v = *(const f16x8*)(qr + (size_t)(b * 2048 + q0 + r) * 512 + h * 64 + c8 * 8);
    *(f16x8*)(smem + ((r * 128 + c8 * 16) ^ ((r & 7) << 4))) = v;
  }
  __syncthreads();
  // hoist Q B-fragments (reused by every MFMA in both passes)
  f16x8 qf[4];
  {
    int r = w * 32 + lo;
#pragma unroll
    for (int ks = 0; ks < 4; ++ks)
      qf[ks] = *(const f16x8*)(smem + ((r * 128 + ks * 32 + hi * 16) ^ ((r & 7) << 4)));
  }

  // ---- pass 1: softmax denominator ----
  float lsum = 0.f;
  for (int kb = 0; kb < 16; ++kb) {
#pragma unroll
    for (int i = 0; i < 8; ++i) {
      int idx = tid + 128 * i; int r = idx >> 3, c8 = idx & 7;
      f16x8 v = *(const f16x8*)(kr + (size_t)(b * 2048 + kb * 128 + r) * 512 + h * 64 + c8 * 8);
      *(f16x8*)(smem + 8192 + ((r * 128 + c8 * 16) ^ ((r & 7) << 4))) = v;
    }
    __syncthreads();
#pragma unroll
    for (int ks4 = 0; ks4 < 4; ++ks4) {
      f32x16 acc = zero16();
      int krw = ks4 * 32 + lo;
#pragma unroll
      for (int ks = 0; ks < 4; ++ks) {
        f16x8 kf = *(const f16x8*)(smem + 8192 + ((krw * 128 + ks * 32 + hi * 16) ^ ((krw & 7) << 4)));
        acc = __builtin_amdgcn_mfma_f32_32x32x16_f16(kf, qf[ks], acc, 0, 0, 0);
      }
      if (!mflag) {
#pragma unroll
        for (int r = 0; r < 16; ++r) lsum += exp2f(acc[r] * C);
      } else {
#pragma unroll
        for (int r = 0; r < 16; ++r) {
          int kg = kb * 128 + ks4 * 32 + (r & 3) + 8 * ((r >> 2) & 3) + 4 * hi;
          float mv = mask[(size_t)(b * 2048 + qw) * 2048 + kg];
          lsum += exp2f((acc[r] - 1e9f * mv) * C);
        }
      }
    }
    __syncthreads();
  }
  lsum += __shfl_xor(lsum, 32);
  const float inv = 1.0f / lsum;

  // ---- pass 2: scores + PV ----
  f32x16 oacc[2];
  oacc[0] = zero16();
  oacc[1] = zero16();
  char* pw = smem + 40960 + (w << 12);
  for (int kb = 0; kb < 16; ++kb) {
#pragma unroll
    for (int i = 0; i < 8; ++i) {
      int idx = tid + 128 * i; int r = idx >> 3, c8 = idx & 7;
      f16x8 v = *(const f16x8*)(kr + (size_t)(b * 2048 + kb * 128 + r) * 512 + h * 64 + c8 * 8);
      *(f16x8*)(smem + 8192 + ((r * 128 + c8 * 16) ^ ((r & 7) << 4))) = v;
    }
#pragma unroll
    for (int i = 0; i < 8; ++i) {
      int idx = tid + 128 * i; int d = idx >> 4, k8 = idx & 15;
      f16x8 v = *(const f16x8*)(vt + (size_t)((b * 8 + h) * 64 + d) * 2048 + kb * 128 + k8 * 8);
      *(f16x8*)(smem + 24576 + ((d * 256 + k8 * 16) ^ ((d & 7) << 4))) = v;
    }
    __syncthreads();
#pragma unroll
    for (int ks4 = 0; ks4 < 4; ++ks4) {
      f32x16 acc = zero16();
      int krw = ks4 * 32 + lo;
#pragma unroll
      for (int ks = 0; ks < 4; ++ks) {
        f16x8 kf = *(const f16x8*)(smem + 8192 + ((krw * 128 + ks * 32 + hi * 16) ^ ((krw & 7) << 4)));
        acc = __builtin_amdgcn_mfma_f32_32x32x16_f16(kf, qf[ks], acc, 0, 0, 0);
      }
      float p[16];
      if (!mflag) {
#pragma unroll
        for (int r = 0; r < 16; ++r) p[r] = exp2f(acc[r] * C) * inv;
      } else {
#pragma unroll
        for (int r = 0; r < 16; ++r) {
          int kg = kb * 128 + ks4 * 32 + (r & 3) + 8 * ((r >> 2) & 3) + 4 * hi;
          float mv = mask[(size_t)(b * 2048 + qw) * 2048 + kg];
          p[r] = exp2f((acc[r] - 1e9f * mv) * C) * inv;
        }
      }
      // transpose p through LDS (perfect col^row swizzle), coalesced stores
#pragma unroll
      for (int r = 0; r < 16; ++r) {
        int krow = (r & 3) + 8 * ((r >> 2) & 3) + 4 * hi;
        *(float*)(pw + krow * 128 + (((lo ^ krow) & 31) << 2)) = p[r];
      }
      float* srow = scores + (size_t)(bh * 2048 + q0 + w * 32) * 2048 + kb * 128 + ks4 * 32 + lo;
#pragma unroll
      for (int j = 0; j < 16; ++j) {
        int qq = 2 * j + hi;
        float v = *(const float*)(pw + lo * 128 + (((qq ^ lo) & 31) << 2));
        srow[(size_t)qq * 2048] = v;
      }
      // PV: build P^T B-fragments in-register, A = V^T rows from Vs
#pragma unroll
      for (int kb2 = 0; kb2 < 2; ++kb2) {
        unsigned X0 = pkh(p[8 * kb2 + 0], p[8 * kb2 + 1]);
        unsigned X1 = pkh(p[8 * kb2 + 2], p[8 * kb2 + 3]);
        unsigned Y0 = pkh(p[8 * kb2 + 4], p[8 * kb2 + 5]);
        unsigned Y1 = pkh(p[8 * kb2 + 6], p[8 * kb2 + 7]);
        unsigned w0, w1, w2, w3;
        swap32(X0, Y0, hi, w0, w2);
        swap32(X1, Y1, hi, w1, w3);
        union { unsigned u[4]; f16x8 v; } pf;
        pf.u[0] = w0; pf.u[1] = w1; pf.u[2] = w2; pf.u[3] = w3;
        int col = ks4 * 64 + kb2 * 32 + hi * 16;  // byte col in Vs row
#pragma unroll
        for (int dt = 0; dt < 2; ++dt) {
          int d = dt * 32 + lo;
          f16x8 vf = *(const f16x8*)(smem + 24576 + ((d * 256 + col) ^ ((d & 7) << 4)));
          oacc[dt] = __builtin_amdgcn_mfma_f32_32x32x16_f16(vf, pf.v, oacc[dt], 0, 0, 0);
        }
      }
    }
    __syncthreads();
  }
  // write embeds [b][s][h*64+d] f16 (out^T regs: col=q, rows=d)
  _Float16* erow = embeds + (size_t)(b * 2048 + qw) * 512 + h * 64;
#pragma unroll
  for (int dt = 0; dt < 2; ++dt)
#pragma unroll
    for (int a = 0; a < 4; ++a) {
      int d = dt * 32 + 8 * a + 4 * hi;
      uint2 uu;
      uu.x = pkh(oacc[dt][4 * a + 0], oacc[dt][4 * a + 1]);
      uu.y = pkh(oacc[dt][4 * a + 2], oacc[dt][4 * a + 3]);
      *(uint2*)(erow + d) = uu;
    }
}

// ---------------------------------------------------------------------------
extern "C" void kernel_launch(void* const* d_in, const int* in_sizes, int n_in,
                              void* d_out, int out_size, void* d_ws, size_t ws_size,
                              hipStream_t stream) {
  const float* querys = (const float*)d_in[0];
  const float* keys   = (const float*)d_in[1];
  const float* values = (const float*)d_in[2];
  const float* mask   = (const float*)d_in[3];
  const float* Wq = (const float*)d_in[4];
  const float* Wk = (const float*)d_in[5];
  const float* Wv = (const float*)d_in[6];
  const float* Wo = (const float*)d_in[7];

  char* ws = (char*)d_ws;
  const size_t MB4 = 4194304;  // 4096*512*2 bytes
  _Float16* q_p = (_Float16*)(ws + 0 * MB4);
  _Float16* k_p = (_Float16*)(ws + 1 * MB4);
  _Float16* q_r = (_Float16*)(ws + 2 * MB4);
  _Float16* k_r = (_Float16*)(ws + 3 * MB4);
  _Float16* v_t = (_Float16*)(ws + 4 * MB4);
  _Float16* emb = (_Float16*)(ws + 5 * MB4);
  int* flag = (int*)(ws + 6 * MB4);

  float* out_emb = (float*)d_out;
  float* out_sc  = out_emb + (size_t)4096 * 512;

  hipMemsetAsync(flag, 0, 4, stream);
  mask_scan<<<dim3(1024), 256, 0, stream>>>(mask, flag);

  gemm_kernel<0><<<dim3(4, 64), 256, 0, stream>>>((const void*)querys, Wq, (void*)q_p);
  gemm_kernel<0><<<dim3(4, 64), 256, 0, stream>>>((const void*)keys,   Wk, (void*)k_p);
  gemm_kernel<1><<<dim3(4, 64), 256, 0, stream>>>((const void*)values, Wv, (void*)v_t);

  rope_kernel<<<dim3(4096, 2), 256, 0, stream>>>(q_p, k_p, q_r, k_r);

  attn_kernel<<<dim3(32, 16), 128, 0, stream>>>(q_r, k_r, v_t, mask, flag, out_sc, emb);

  gemm_kernel<2><<<dim3(4, 64), 256, 0, stream>>>((const void*)emb, Wo, (void*)d_out);
}

// Round 2
// 252.577 us; speedup vs baseline: 1.1760x; 1.1760x over previous
//
#include <hip/hip_runtime.h>
#include <hip/hip_fp16.h>

typedef _Float16 f16x8 __attribute__((ext_vector_type(8)));
typedef float f32x16 __attribute__((ext_vector_type(16)));

#define LOG2E 1.44269504088896340736f

typedef __attribute__((address_space(1))) const unsigned char gl_byte;
typedef __attribute__((address_space(3))) unsigned char lds_byte;

#define GLOAD_LDS16(g, l) \
  __builtin_amdgcn_global_load_lds((const gl_byte*)(g), (lds_byte*)(l), 16, 0, 0)

static __device__ __forceinline__ f32x16 zero16() {
  f32x16 z;
#pragma unroll
  for (int i = 0; i < 16; ++i) z[i] = 0.0f;
  return z;
}

static __device__ __forceinline__ unsigned pkh(float a, float b) {
  union { _Float16 h[2]; unsigned u; } t;
  t.h[0] = (_Float16)a; t.h[1] = (_Float16)b;
  return t.u;
}

// exchange: a = (hi ? partner's y : own x), c = (hi ? own y : partner's x)
static __device__ __forceinline__ void swap32(unsigned x, unsigned y, int hi,
                                              unsigned& a, unsigned& c) {
  unsigned py = (unsigned)__shfl_xor((int)y, 32);
  unsigned px = (unsigned)__shfl_xor((int)x, 32);
  a = hi ? py : x;
  c = hi ? y : px;
}

// ---------------------------------------------------------------------------
// GEMM: out = A @ W^T.  A: [4096 x 512], W: [512 x 512] f32.
// Tile 64(M) x 128(N), BK=64, 256 threads (4 waves, 2x2).
// MODE 0: A f32, epilogue applies RoPE, out f16 row-major [4096][512]
// MODE 1: A f32, out scattered as v_t[b][h][d][s] f16
// MODE 2: A = sum of two f32 partial arrays (PV partials), out f32 (d_out)
// ---------------------------------------------------------------------------
template <int MODE>
__global__ __launch_bounds__(256) void gemm_kernel(const void* __restrict__ Ap,
                                                   const float* __restrict__ W,
                                                   void* __restrict__ outp) {
  __shared__ char smem[8192 + 16384];  // As [64][64] f16, Ws [128][64] f16
  const int tid = threadIdx.x;
  const int l = tid & 63, lo = l & 31, hi = l >> 5;
  const int w = tid >> 6, wm = w >> 1, wn = w & 1;
  const int m0 = blockIdx.y * 64, n0 = blockIdx.x * 128;

  f32x16 acc[2];
  acc[0] = zero16();
  acc[1] = zero16();

  for (int kb = 0; kb < 8; ++kb) {
    // stage A -> As (f16, swizzled)
    if constexpr (MODE == 2) {
      const float* P0 = (const float*)Ap;
      const float* P1 = P0 + (size_t)4096 * 512;
#pragma unroll
      for (int i = 0; i < 4; ++i) {
        int idx = tid + 256 * i; int r = idx >> 4, c4 = idx & 15;
        size_t off = (size_t)(m0 + r) * 512 + kb * 64 + c4 * 4;
        float4 x = *(const float4*)(P0 + off);
        float4 y = *(const float4*)(P1 + off);
        uint2 uu; uu.x = pkh(x.x + y.x, x.y + y.y); uu.y = pkh(x.z + y.z, x.w + y.w);
        *(uint2*)(smem + ((r * 128 + c4 * 8) ^ ((r & 7) << 4))) = uu;
      }
    } else {
      const float* A = (const float*)Ap;
#pragma unroll
      for (int i = 0; i < 4; ++i) {
        int idx = tid + 256 * i; int r = idx >> 4, c4 = idx & 15;
        float4 v = *(const float4*)(A + (size_t)(m0 + r) * 512 + kb * 64 + c4 * 4);
        uint2 uu; uu.x = pkh(v.x, v.y); uu.y = pkh(v.z, v.w);
        *(uint2*)(smem + ((r * 128 + c4 * 8) ^ ((r & 7) << 4))) = uu;
      }
    }
    // stage W -> Ws
#pragma unroll
    for (int i = 0; i < 8; ++i) {
      int idx = tid + 256 * i; int r = idx >> 4, c4 = idx & 15;
      float4 v = *(const float4*)(W + (size_t)(n0 + r) * 512 + kb * 64 + c4 * 4);
      uint2 uu; uu.x = pkh(v.x, v.y); uu.y = pkh(v.z, v.w);
      *(uint2*)(smem + 8192 + ((r * 128 + c4 * 8) ^ ((r & 7) << 4))) = uu;
    }
    __syncthreads();
#pragma unroll
    for (int ks = 0; ks < 4; ++ks) {
      int ra = wm * 32 + lo;
      f16x8 a0 = *(const f16x8*)(smem + ((ra * 128 + ks * 32 + hi * 16) ^ ((ra & 7) << 4)));
      int rb0 = wn * 64 + lo, rb1 = rb0 + 32;
      f16x8 b0 = *(const f16x8*)(smem + 8192 + ((rb0 * 128 + ks * 32 + hi * 16) ^ ((rb0 & 7) << 4)));
      f16x8 b1 = *(const f16x8*)(smem + 8192 + ((rb1 * 128 + ks * 32 + hi * 16) ^ ((rb1 & 7) << 4)));
      acc[0] = __builtin_amdgcn_mfma_f32_32x32x16_f16(a0, b0, acc[0], 0, 0, 0);
      acc[1] = __builtin_amdgcn_mfma_f32_32x32x16_f16(a0, b1, acc[1], 0, 0, 0);
    }
    __syncthreads();
  }

  if constexpr (MODE == 0) {
    _Float16* out = (_Float16*)outp;
#pragma unroll
    for (int nt = 0; nt < 2; ++nt) {
      int n = n0 + wn * 64 + nt * 32 + lo;
      int odd = lo & 1;
      int ii = (n >> 1) & 255;
      float fr = exp2f(-(float)ii * 0.05190512648261504f);
#pragma unroll
      for (int r = 0; r < 16; ++r) {
        int m = m0 + wm * 32 + (r & 3) + 8 * ((r >> 2) & 3) + 4 * hi;
        float a = acc[nt][r];
        float bb = __shfl_xor(a, 1);
        float xe = odd ? bb : a, xo = odd ? a : bb;
        float ang = (float)(m & 2047) * fr;
        float sn, cs;
        sincosf(ang, &sn, &cs);
        float res = odd ? (xo * cs + xe * sn) : (xe * cs - xo * sn);
        out[(size_t)m * 512 + ii + (odd ? 256 : 0)] = (_Float16)res;
      }
    }
  } else if constexpr (MODE == 1) {
    _Float16* vt = (_Float16*)outp;
#pragma unroll
    for (int nt = 0; nt < 2; ++nt) {
      int n = n0 + wn * 64 + nt * 32 + lo;
      int hh = n >> 6, d = n & 63;
#pragma unroll
      for (int a = 0; a < 4; ++a) {
        int m = m0 + wm * 32 + 8 * a + 4 * hi;
        int b_ = m >> 11, s = m & 2047;
        uint2 uu;
        uu.x = pkh(acc[nt][4 * a + 0], acc[nt][4 * a + 1]);
        uu.y = pkh(acc[nt][4 * a + 2], acc[nt][4 * a + 3]);
        *(uint2*)(vt + (size_t)((b_ * 8 + hh) * 64 + d) * 2048 + s) = uu;
      }
    }
  } else {
    float* out = (float*)outp;
#pragma unroll
    for (int nt = 0; nt < 2; ++nt) {
      int n = n0 + wn * 64 + nt * 32 + lo;
#pragma unroll
      for (int r = 0; r < 16; ++r) {
        int m = m0 + wm * 32 + (r & 3) + 8 * ((r >> 2) & 3) + 4 * hi;
        out[(size_t)m * 512 + n] = acc[nt][r];
      }
    }
  }
}

// ---------------------------------------------------------------------------
// Reduce attn_mask to a nonzero flag (fast-path detector; zeros in harness).
// ---------------------------------------------------------------------------
__global__ __launch_bounds__(256) void mask_scan(const float* __restrict__ mask,
                                                 int* __restrict__ flag) {
  const int n4 = 2 * 2048 * 2048 / 4;
  bool nz = false;
  for (int i = blockIdx.x * 256 + threadIdx.x; i < n4; i += gridDim.x * 256) {
    float4 v = ((const float4*)mask)[i];
    nz |= (v.x != 0.f) || (v.y != 0.f) || (v.z != 0.f) || (v.w != 0.f);
  }
  if (__any(nz) && (threadIdx.x & 63) == 0) atomicOr(flag, 1);
}

// ---------------------------------------------------------------------------
// Pass 1: softmax denominators, k-split 4.  grid (32 qt, 16 bh, 4 ks).
// Writes partial row sums to lsums[ks][bh][q].
// ---------------------------------------------------------------------------
__global__ __launch_bounds__(128) void lsum_kernel(
    const _Float16* __restrict__ qr, const _Float16* __restrict__ kr,
    const float* __restrict__ mask, const int* __restrict__ flagp,
    float* __restrict__ lsums) {
  __shared__ char smem[8192 + 16384];  // Qs [64][64] @0, Ks [128][64] @8192
  const int tid = threadIdx.x;
  const int w = tid >> 6, l = tid & 63, lo = l & 31, hi = l >> 5;
  const int bh = blockIdx.y, b = bh >> 3, h = bh & 7;
  const int q0 = blockIdx.x * 64, z = blockIdx.z;
  const int mflag = *flagp;
  const float C = 0.125f * LOG2E;
  const int qw = q0 + w * 32 + lo;

  // stage Q tile (manual, once)
#pragma unroll
  for (int i = 0; i < 4; ++i) {
    int idx = tid + 128 * i; int r = idx >> 3, c8 = idx & 7;
    f16x8 v = *(const f16x8*)(qr + (size_t)(b * 2048 + q0 + r) * 512 + h * 64 + c8 * 8);
    *(f16x8*)(smem + ((r * 128 + c8 * 16) ^ ((r & 7) << 4))) = v;
  }
  __syncthreads();
  f16x8 qf[4];
  {
    int r = w * 32 + lo;
#pragma unroll
    for (int ks = 0; ks < 4; ++ks)
      qf[ks] = *(const f16x8*)(smem + ((r * 128 + ks * 32 + hi * 16) ^ ((r & 7) << 4)));
  }

  float lsum = 0.f;
  for (int kb = z * 4; kb < z * 4 + 4; ++kb) {
    // K -> LDS via async DMA, pre-swizzled global source
#pragma unroll
    for (int it = 0; it < 8; ++it) {
      int s = it * 128 + w * 64 + l;
      int r = s >> 3, c8 = (s & 7) ^ (r & 7);
      const _Float16* g = kr + (size_t)(b * 2048 + kb * 128 + r) * 512 + h * 64 + c8 * 8;
      GLOAD_LDS16(g, smem + 8192 + (it * 128 + w * 64) * 16);
    }
    __syncthreads();
#pragma unroll
    for (int ks4 = 0; ks4 < 4; ++ks4) {
      f32x16 acc = zero16();
      int krw = ks4 * 32 + lo;
#pragma unroll
      for (int ks = 0; ks < 4; ++ks) {
        f16x8 kf = *(const f16x8*)(smem + 8192 + ((krw * 128 + ks * 32 + hi * 16) ^ ((krw & 7) << 4)));
        acc = __builtin_amdgcn_mfma_f32_32x32x16_f16(kf, qf[ks], acc, 0, 0, 0);
      }
      if (!mflag) {
#pragma unroll
        for (int r = 0; r < 16; ++r) lsum += exp2f(acc[r] * C);
      } else {
#pragma unroll
        for (int r = 0; r < 16; ++r) {
          int kg = kb * 128 + ks4 * 32 + (r & 3) + 8 * ((r >> 2) & 3) + 4 * hi;
          float mv = mask[(size_t)(b * 2048 + qw) * 2048 + kg];
          lsum += exp2f((acc[r] - 1e9f * mv) * C);
        }
      }
    }
    __syncthreads();
  }
  lsum += __shfl_xor(lsum, 32);
  if (hi == 0) lsums[(size_t)(z * 16 + bh) * 2048 + qw] = lsum;
}

// ---------------------------------------------------------------------------
// Pass 2: scores + partial PV, k-split 2.  grid (32 qt, 16 bh, 2 ks), 128 thr.
// LDS 40KB: Ks [128][64] @0, Vs(V^T) [64][128] @16384, Q/tr @32768 (8KB).
// ---------------------------------------------------------------------------
__global__ __launch_bounds__(128) void attn_kernel(
    const _Float16* __restrict__ qr, const _Float16* __restrict__ kr,
    const _Float16* __restrict__ vt, const float* __restrict__ mask,
    const int* __restrict__ flagp, const float* __restrict__ lsums,
    float* __restrict__ scores, float* __restrict__ opart) {
  __shared__ char smem[40960];
  const int tid = threadIdx.x;
  const int w = tid >> 6, l = tid & 63, lo = l & 31, hi = l >> 5;
  const int bh = blockIdx.y, b = bh >> 3, h = bh & 7;
  const int q0 = blockIdx.x * 64, z = blockIdx.z;
  const int mflag = *flagp;
  const float C = 0.125f * LOG2E;
  const int qw = q0 + w * 32 + lo;

  // stage Q into the tr region (reused after fragment hoist)
#pragma unroll
  for (int i = 0; i < 4; ++i) {
    int idx = tid + 128 * i; int r = idx >> 3, c8 = idx & 7;
    f16x8 v = *(const f16x8*)(qr + (size_t)(b * 2048 + q0 + r) * 512 + h * 64 + c8 * 8);
    *(f16x8*)(smem + 32768 + ((r * 128 + c8 * 16) ^ ((r & 7) << 4))) = v;
  }
  __syncthreads();
  f16x8 qf[4];
  {
    int r = w * 32 + lo;
#pragma unroll
    for (int ks = 0; ks < 4; ++ks)
      qf[ks] = *(const f16x8*)(smem + 32768 + ((r * 128 + ks * 32 + hi * 16) ^ ((r & 7) << 4)));
  }

  // denominator: sum 4 partials (deterministic)
  float lsum = 0.f;
#pragma unroll
  for (int zz = 0; zz < 4; ++zz) lsum += lsums[(size_t)(zz * 16 + bh) * 2048 + qw];
  const float inv = 1.0f / lsum;

  f32x16 oacc[2];
  oacc[0] = zero16();
  oacc[1] = zero16();
  char* trw = smem + 32768 + (w << 12);  // per-wave [32 q][32 k] f32, swz k^q

  for (int kb = z * 8; kb < z * 8 + 8; ++kb) {
    // K tile async
#pragma unroll
    for (int it = 0; it < 8; ++it) {
      int s = it * 128 + w * 64 + l;
      int r = s >> 3, c8 = (s & 7) ^ (r & 7);
      const _Float16* g = kr + (size_t)(b * 2048 + kb * 128 + r) * 512 + h * 64 + c8 * 8;
      GLOAD_LDS16(g, smem + (it * 128 + w * 64) * 16);
    }
    // V tile async (V^T [64 d][128 k])
#pragma unroll
    for (int it = 0; it < 8; ++it) {
      int s = it * 128 + w * 64 + l;
      int d = s >> 4, t = s & 15, c8 = (t & 8) | ((t & 7) ^ (d & 7));
      const _Float16* g = vt + (size_t)((b * 8 + h) * 64 + d) * 2048 + kb * 128 + c8 * 8;
      GLOAD_LDS16(g, smem + 16384 + (it * 128 + w * 64) * 16);
    }
    __syncthreads();
#pragma unroll
    for (int ks4 = 0; ks4 < 4; ++ks4) {
      f32x16 acc = zero16();
      int krw = ks4 * 32 + lo;
#pragma unroll
      for (int ks = 0; ks < 4; ++ks) {
        f16x8 kf = *(const f16x8*)(smem + ((krw * 128 + ks * 32 + hi * 16) ^ ((krw & 7) << 4)));
        acc = __builtin_amdgcn_mfma_f32_32x32x16_f16(kf, qf[ks], acc, 0, 0, 0);
      }
      float p[16];
      if (!mflag) {
#pragma unroll
        for (int r = 0; r < 16; ++r) p[r] = exp2f(acc[r] * C) * inv;
      } else {
#pragma unroll
        for (int r = 0; r < 16; ++r) {
          int kg = kb * 128 + ks4 * 32 + (r & 3) + 8 * ((r >> 2) & 3) + 4 * hi;
          float mv = mask[(size_t)(b * 2048 + qw) * 2048 + kg];
          p[r] = exp2f((acc[r] - 1e9f * mv) * C) * inv;
        }
      }
      // transpose via LDS: element (q,k) at q*128 + ((k^q)&31)*4
#pragma unroll
      for (int r = 0; r < 16; ++r) {
        int krow = (r & 3) + 8 * ((r >> 2) & 3) + 4 * hi;
        *(float*)(trw + lo * 128 + (((krow ^ lo) & 31) << 2)) = p[r];
      }
      // read back float4 (component-permuted by q&3), coalesced stores
      float* srow = scores + (size_t)(bh * 2048 + q0 + w * 32) * 2048 + kb * 128 + ks4 * 32;
      {
        int qrd = l >> 3, m4 = (l & 7) << 2;
#pragma unroll
        for (int j = 0; j < 4; ++j) {
          int q = qrd + 8 * j;
          int g = (m4 ^ (q & 28)) & 31;
          float4 v = *(const float4*)(trw + q * 128 + g * 4);
          const float* vf = (const float*)&v;
          int px = q & 3;
          float4 o;
          o.x = vf[0 ^ px]; o.y = vf[1 ^ px]; o.z = vf[2 ^ px]; o.w = vf[3 ^ px];
          *(float4*)(srow + (size_t)q * 2048 + m4) = o;
        }
      }
      // PV: build P^T fragments in-register, A = V^T rows from Vs
#pragma unroll
      for (int kb2 = 0; kb2 < 2; ++kb2) {
        unsigned X0 = pkh(p[8 * kb2 + 0], p[8 * kb2 + 1]);
        unsigned X1 = pkh(p[8 * kb2 + 2], p[8 * kb2 + 3]);
        unsigned Y0 = pkh(p[8 * kb2 + 4], p[8 * kb2 + 5]);
        unsigned Y1 = pkh(p[8 * kb2 + 6], p[8 * kb2 + 7]);
        unsigned w0, w1, w2, w3;
        swap32(X0, Y0, hi, w0, w2);
        swap32(X1, Y1, hi, w1, w3);
        union { unsigned u[4]; f16x8 v; } pf;
        pf.u[0] = w0; pf.u[1] = w1; pf.u[2] = w2; pf.u[3] = w3;
        int col = ks4 * 64 + kb2 * 32 + hi * 16;  // byte col in Vs row
#pragma unroll
        for (int dt = 0; dt < 2; ++dt) {
          int d = dt * 32 + lo;
          f16x8 vf2 = *(const f16x8*)(smem + 16384 + ((d * 256 + col) ^ ((d & 7) << 4)));
          oacc[dt] = __builtin_amdgcn_mfma_f32_32x32x16_f16(vf2, pf.v, oacc[dt], 0, 0, 0);
        }
      }
    }
    __syncthreads();
  }
  // partial PV out (f32): opart[z][b*2048+qw][h*64+d]
  float* orow = opart + (size_t)z * 4096 * 512 + (size_t)(b * 2048 + qw) * 512 + h * 64;
#pragma unroll
  for (int dt = 0; dt < 2; ++dt)
#pragma unroll
    for (int a = 0; a < 4; ++a) {
      int d = dt * 32 + 8 * a + 4 * hi;
      float4 o;
      o.x = oacc[dt][4 * a + 0]; o.y = oacc[dt][4 * a + 1];
      o.z = oacc[dt][4 * a + 2]; o.w = oacc[dt][4 * a + 3];
      *(float4*)(orow + d) = o;
    }
}

// ---------------------------------------------------------------------------
extern "C" void kernel_launch(void* const* d_in, const int* in_sizes, int n_in,
                              void* d_out, int out_size, void* d_ws, size_t ws_size,
                              hipStream_t stream) {
  const float* querys = (const float*)d_in[0];
  const float* keys   = (const float*)d_in[1];
  const float* values = (const float*)d_in[2];
  const float* mask   = (const float*)d_in[3];
  const float* Wq = (const float*)d_in[4];
  const float* Wk = (const float*)d_in[5];
  const float* Wv = (const float*)d_in[6];
  const float* Wo = (const float*)d_in[7];

  char* ws = (char*)d_ws;
  const size_t MB = 1048576;
  _Float16* q_r  = (_Float16*)(ws + 0 * MB);
  _Float16* k_r  = (_Float16*)(ws + 4 * MB);
  _Float16* v_t  = (_Float16*)(ws + 8 * MB);
  float*    opart = (float*)(ws + 12 * MB);   // [2][4096][512] f32 = 16MB
  float*    lsums = (float*)(ws + 28 * MB);   // [4][16][2048] f32 = 512KB
  int*      flag  = (int*)(ws + 29 * MB);

  float* out_sc = (float*)d_out + (size_t)4096 * 512;

  hipMemsetAsync(flag, 0, 4, stream);
  mask_scan<<<dim3(1024), 256, 0, stream>>>(mask, flag);

  gemm_kernel<0><<<dim3(4, 64), 256, 0, stream>>>((const void*)querys, Wq, (void*)q_r);
  gemm_kernel<0><<<dim3(4, 64), 256, 0, stream>>>((const void*)keys,   Wk, (void*)k_r);
  gemm_kernel<1><<<dim3(4, 64), 256, 0, stream>>>((const void*)values, Wv, (void*)v_t);

  lsum_kernel<<<dim3(32, 16, 4), 128, 0, stream>>>(q_r, k_r, mask, flag, lsums);

  attn_kernel<<<dim3(32, 16, 2), 128, 0, stream>>>(q_r, k_r, v_t, mask, flag, lsums,
                                                   out_sc, opart);

  gemm_kernel<2><<<dim3(4, 64), 256, 0, stream>>>((const void*)opart, Wo, (void*)d_out);
}

// Round 3
// 209.543 us; speedup vs baseline: 1.4176x; 1.2054x over previous
//
#include <hip/hip_runtime.h>
#include <hip/hip_fp16.h>

typedef _Float16 f16x8 __attribute__((ext_vector_type(8)));
typedef float f32x16 __attribute__((ext_vector_type(16)));

#define LOG2E 1.44269504088896340736f

typedef __attribute__((address_space(1))) const unsigned char gl_byte;
typedef __attribute__((address_space(3))) unsigned char lds_byte;

#define GLOAD_LDS16(g, l) \
  __builtin_amdgcn_global_load_lds((const gl_byte*)(g), (lds_byte*)(l), 16, 0, 0)

static __device__ __forceinline__ f32x16 zero16() {
  f32x16 z;
#pragma unroll
  for (int i = 0; i < 16; ++i) z[i] = 0.0f;
  return z;
}

static __device__ __forceinline__ unsigned pkh(float a, float b) {
  union { _Float16 h[2]; unsigned u; } t;
  t.h[0] = (_Float16)a; t.h[1] = (_Float16)b;
  return t.u;
}

// exchange: a = (hi ? partner's y : own x), c = (hi ? own y : partner's x)
static __device__ __forceinline__ void swap32(unsigned x, unsigned y, int hi,
                                              unsigned& a, unsigned& c) {
  unsigned py = (unsigned)__shfl_xor((int)y, 32);
  unsigned px = (unsigned)__shfl_xor((int)x, 32);
  a = hi ? py : x;
  c = hi ? y : px;
}

// stage one 64x64-half K tile (8KB) into LDS, linear dest, pre-swizzled source
static __device__ __forceinline__ void stage_k64(char* dst,
                                                 const _Float16* __restrict__ kr,
                                                 int b, int h, int kb, int tid) {
#pragma unroll
  for (int it = 0; it < 4; ++it) {
    int s = it * 128 + tid;
    int r = s >> 3, c8 = (s & 7) ^ (r & 7);
    const _Float16* g = kr + (size_t)(b * 2048 + kb * 64 + r) * 512 + h * 64 + c8 * 8;
    GLOAD_LDS16(g, dst + (it * 128 + (tid & 64)) * 16);
  }
}

// ---------------------------------------------------------------------------
// Fused projections: z=0 -> rope(q@Wq^T), z=1 -> rope(k@Wk^T), z=2 -> v_t.
// Tile 64(M) x 128(N), BK=64, 256 threads (4 waves, 2x2). grid (4, 64, 3).
// ---------------------------------------------------------------------------
__global__ __launch_bounds__(256) void proj_kernel(
    const float* __restrict__ qin, const float* __restrict__ kin,
    const float* __restrict__ vin, const float* __restrict__ Wq,
    const float* __restrict__ Wk, const float* __restrict__ Wv,
    _Float16* __restrict__ q_r, _Float16* __restrict__ k_r,
    _Float16* __restrict__ v_t) {
  __shared__ char smem[8192 + 16384];  // As [64][64] f16, Ws [128][64] f16
  const int tid = threadIdx.x;
  const int l = tid & 63, lo = l & 31, hi = l >> 5;
  const int w = tid >> 6, wm = w >> 1, wn = w & 1;
  const int m0 = blockIdx.y * 64, n0 = blockIdx.x * 128;
  const int zz = blockIdx.z;
  const float* A = zz == 0 ? qin : zz == 1 ? kin : vin;
  const float* W = zz == 0 ? Wq : zz == 1 ? Wk : Wv;

  f32x16 acc[2];
  acc[0] = zero16();
  acc[1] = zero16();

  for (int kb = 0; kb < 8; ++kb) {
#pragma unroll
    for (int i = 0; i < 4; ++i) {
      int idx = tid + 256 * i; int r = idx >> 4, c4 = idx & 15;
      float4 v = *(const float4*)(A + (size_t)(m0 + r) * 512 + kb * 64 + c4 * 4);
      uint2 uu; uu.x = pkh(v.x, v.y); uu.y = pkh(v.z, v.w);
      *(uint2*)(smem + ((r * 128 + c4 * 8) ^ ((r & 7) << 4))) = uu;
    }
#pragma unroll
    for (int i = 0; i < 8; ++i) {
      int idx = tid + 256 * i; int r = idx >> 4, c4 = idx & 15;
      float4 v = *(const float4*)(W + (size_t)(n0 + r) * 512 + kb * 64 + c4 * 4);
      uint2 uu; uu.x = pkh(v.x, v.y); uu.y = pkh(v.z, v.w);
      *(uint2*)(smem + 8192 + ((r * 128 + c4 * 8) ^ ((r & 7) << 4))) = uu;
    }
    __syncthreads();
#pragma unroll
    for (int ks = 0; ks < 4; ++ks) {
      int ra = wm * 32 + lo;
      f16x8 a0 = *(const f16x8*)(smem + ((ra * 128 + ks * 32 + hi * 16) ^ ((ra & 7) << 4)));
      int rb0 = wn * 64 + lo, rb1 = rb0 + 32;
      f16x8 b0 = *(const f16x8*)(smem + 8192 + ((rb0 * 128 + ks * 32 + hi * 16) ^ ((rb0 & 7) << 4)));
      f16x8 b1 = *(const f16x8*)(smem + 8192 + ((rb1 * 128 + ks * 32 + hi * 16) ^ ((rb1 & 7) << 4)));
      acc[0] = __builtin_amdgcn_mfma_f32_32x32x16_f16(a0, b0, acc[0], 0, 0, 0);
      acc[1] = __builtin_amdgcn_mfma_f32_32x32x16_f16(a0, b1, acc[1], 0, 0, 0);
    }
    __syncthreads();
  }

  if (zz < 2) {
    _Float16* out = zz ? k_r : q_r;
#pragma unroll
    for (int nt = 0; nt < 2; ++nt) {
      int n = n0 + wn * 64 + nt * 32 + lo;
      int odd = lo & 1;
      int ii = (n >> 1) & 255;
      float fr = exp2f(-(float)ii * 0.05190512648261504f);
#pragma unroll
      for (int r = 0; r < 16; ++r) {
        int m = m0 + wm * 32 + (r & 3) + 8 * ((r >> 2) & 3) + 4 * hi;
        float a = acc[nt][r];
        float bb = __shfl_xor(a, 1);
        float xe = odd ? bb : a, xo = odd ? a : bb;
        float ang = (float)(m & 2047) * fr;
        float sn, cs;
        sincosf(ang, &sn, &cs);
        float res = odd ? (xo * cs + xe * sn) : (xe * cs - xo * sn);
        out[(size_t)m * 512 + ii + (odd ? 256 : 0)] = (_Float16)res;
      }
    }
  } else {
#pragma unroll
    for (int nt = 0; nt < 2; ++nt) {
      int n = n0 + wn * 64 + nt * 32 + lo;
      int hh = n >> 6, d = n & 63;
#pragma unroll
      for (int a = 0; a < 4; ++a) {
        int m = m0 + wm * 32 + 8 * a + 4 * hi;
        int b_ = m >> 11, s = m & 2047;
        uint2 uu;
        uu.x = pkh(acc[nt][4 * a + 0], acc[nt][4 * a + 1]);
        uu.y = pkh(acc[nt][4 * a + 2], acc[nt][4 * a + 3]);
        *(uint2*)(v_t + (size_t)((b_ * 8 + hh) * 64 + d) * 2048 + s) = uu;
      }
    }
  }
}

// ---------------------------------------------------------------------------
// Output GEMM: d_out = (sum of 4 PV partial slabs) @ Wo^T, f32 out.
// ---------------------------------------------------------------------------
__global__ __launch_bounds__(256) void out_gemm(const float* __restrict__ opart,
                                                const float* __restrict__ W,
                                                float* __restrict__ out) {
  __shared__ char smem[8192 + 16384];
  const int tid = threadIdx.x;
  const int l = tid & 63, lo = l & 31, hi = l >> 5;
  const int w = tid >> 6, wm = w >> 1, wn = w & 1;
  const int m0 = blockIdx.y * 64, n0 = blockIdx.x * 128;

  f32x16 acc[2];
  acc[0] = zero16();
  acc[1] = zero16();

  for (int kb = 0; kb < 8; ++kb) {
#pragma unroll
    for (int i = 0; i < 4; ++i) {
      int idx = tid + 256 * i; int r = idx >> 4, c4 = idx & 15;
      size_t off = (size_t)(m0 + r) * 512 + kb * 64 + c4 * 4;
      float4 x = *(const float4*)(opart + off);
      float4 y = *(const float4*)(opart + (size_t)4096 * 512 + off);
      float4 u = *(const float4*)(opart + (size_t)2 * 4096 * 512 + off);
      float4 t = *(const float4*)(opart + (size_t)3 * 4096 * 512 + off);
      uint2 uu;
      uu.x = pkh(x.x + y.x + u.x + t.x, x.y + y.y + u.y + t.y);
      uu.y = pkh(x.z + y.z + u.z + t.z, x.w + y.w + u.w + t.w);
      *(uint2*)(smem + ((r * 128 + c4 * 8) ^ ((r & 7) << 4))) = uu;
    }
#pragma unroll
    for (int i = 0; i < 8; ++i) {
      int idx = tid + 256 * i; int r = idx >> 4, c4 = idx & 15;
      float4 v = *(const float4*)(W + (size_t)(n0 + r) * 512 + kb * 64 + c4 * 4);
      uint2 uu; uu.x = pkh(v.x, v.y); uu.y = pkh(v.z, v.w);
      *(uint2*)(smem + 8192 + ((r * 128 + c4 * 8) ^ ((r & 7) << 4))) = uu;
    }
    __syncthreads();
#pragma unroll
    for (int ks = 0; ks < 4; ++ks) {
      int ra = wm * 32 + lo;
      f16x8 a0 = *(const f16x8*)(smem + ((ra * 128 + ks * 32 + hi * 16) ^ ((ra & 7) << 4)));
      int rb0 = wn * 64 + lo, rb1 = rb0 + 32;
      f16x8 b0 = *(const f16x8*)(smem + 8192 + ((rb0 * 128 + ks * 32 + hi * 16) ^ ((rb0 & 7) << 4)));
      f16x8 b1 = *(const f16x8*)(smem + 8192 + ((rb1 * 128 + ks * 32 + hi * 16) ^ ((rb1 & 7) << 4)));
      acc[0] = __builtin_amdgcn_mfma_f32_32x32x16_f16(a0, b0, acc[0], 0, 0, 0);
      acc[1] = __builtin_amdgcn_mfma_f32_32x32x16_f16(a0, b1, acc[1], 0, 0, 0);
    }
    __syncthreads();
  }

  {
#pragma unroll
    for (int nt = 0; nt < 2; ++nt) {
      int n = n0 + wn * 64 + nt * 32 + lo;
#pragma unroll
      for (int r = 0; r < 16; ++r) {
        int m = m0 + wm * 32 + (r & 3) + 8 * ((r >> 2) & 3) + 4 * hi;
        out[(size_t)m * 512 + n] = acc[nt][r];
      }
    }
  }
}

// ---------------------------------------------------------------------------
// Reduce attn_mask to a nonzero flag (fast-path detector; zeros in harness).
// ---------------------------------------------------------------------------
__global__ __launch_bounds__(256) void mask_scan(const float* __restrict__ mask,
                                                 int* __restrict__ flag) {
  const int n4 = 2 * 2048 * 2048 / 4;
  bool nz = false;
  for (int i = blockIdx.x * 256 + threadIdx.x; i < n4; i += gridDim.x * 256) {
    float4 v = ((const float4*)mask)[i];
    nz |= (v.x != 0.f) || (v.y != 0.f) || (v.z != 0.f) || (v.w != 0.f);
  }
  if (__any(nz) && (threadIdx.x & 63) == 0) atomicOr(flag, 1);
}

// ---------------------------------------------------------------------------
// Pass 1: softmax denominators, k-split 4.  grid (32 qt, 16 bh, 4 z), 128 thr.
// LDS 16KB: K double-buffer 2x8KB.  Q fragments straight from global (L2).
// ---------------------------------------------------------------------------
__global__ __launch_bounds__(128, 4) void lsum_kernel(
    const _Float16* __restrict__ qr, const _Float16* __restrict__ kr,
    const float* __restrict__ mask, const int* __restrict__ flagp,
    float* __restrict__ lsums) {
  __shared__ char smem[16384];
  const int tid = threadIdx.x;
  const int w = tid >> 6, l = tid & 63, lo = l & 31, hi = l >> 5;
  const int bh = blockIdx.y, b = bh >> 3, h = bh & 7;
  const int q0 = blockIdx.x * 64, z = blockIdx.z;
  const int mflag = *flagp;
  const float C = 0.125f * LOG2E;
  const int qw = q0 + w * 32 + lo;

  // Q B-fragments direct from global
  f16x8 qf[4];
  {
    const _Float16* qrow = qr + (size_t)(b * 2048 + qw) * 512 + h * 64 + hi * 8;
#pragma unroll
    for (int ks = 0; ks < 4; ++ks) qf[ks] = *(const f16x8*)(qrow + ks * 16);
  }

  const int kb0 = z * 8;
  stage_k64(smem, kr, b, h, kb0, tid);
  __syncthreads();

  float lsum = 0.f;
  for (int t = 0; t < 8; ++t) {
    const int cur = t & 1, kb = kb0 + t;
    if (t < 7) stage_k64(smem + (cur ^ 1) * 8192, kr, b, h, kb + 1, tid);
    char* kbuf = smem + cur * 8192;
#pragma unroll
    for (int ks4 = 0; ks4 < 2; ++ks4) {
      f32x16 acc = zero16();
      int krw = ks4 * 32 + lo;
#pragma unroll
      for (int ks = 0; ks < 4; ++ks) {
        f16x8 kf = *(const f16x8*)(kbuf + ((krw * 128 + ks * 32 + hi * 16) ^ ((krw & 7) << 4)));
        acc = __builtin_amdgcn_mfma_f32_32x32x16_f16(kf, qf[ks], acc, 0, 0, 0);
      }
      if (!mflag) {
#pragma unroll
        for (int r = 0; r < 16; ++r) lsum += exp2f(acc[r] * C);
      } else {
#pragma unroll
        for (int r = 0; r < 16; ++r) {
          int kg = kb * 64 + ks4 * 32 + (r & 3) + 8 * ((r >> 2) & 3) + 4 * hi;
          float mv = mask[(size_t)(b * 2048 + qw) * 2048 + kg];
          lsum += exp2f((acc[r] - 1e9f * mv) * C);
        }
      }
    }
    __syncthreads();
  }
  lsum += __shfl_xor(lsum, 32);
  if (hi == 0) lsums[(size_t)(z * 16 + bh) * 2048 + qw] = lsum;
}

// ---------------------------------------------------------------------------
// Pass 2: scores + partial PV, k-split 4.  grid (32 qt, 16 bh, 4 z), 128 thr.
// LDS 24KB: K dbuf 2x8KB @0, per-wave f32 transpose @16384.
// Q and V fragments straight from global (L2-resident).
// ---------------------------------------------------------------------------
__global__ __launch_bounds__(128, 3) void attn_kernel(
    const _Float16* __restrict__ qr, const _Float16* __restrict__ kr,
    const _Float16* __restrict__ vt, const float* __restrict__ mask,
    const int* __restrict__ flagp, const float* __restrict__ lsums,
    float* __restrict__ scores, float* __restrict__ opart) {
  __shared__ char smem[24576];
  const int tid = threadIdx.x;
  const int w = tid >> 6, l = tid & 63, lo = l & 31, hi = l >> 5;
  const int bh = blockIdx.y, b = bh >> 3, h = bh & 7;
  const int q0 = blockIdx.x * 64, z = blockIdx.z;
  const int mflag = *flagp;
  const float C = 0.125f * LOG2E;
  const int qw = q0 + w * 32 + lo;

  f16x8 qf[4];
  {
    const _Float16* qrow = qr + (size_t)(b * 2048 + qw) * 512 + h * 64 + hi * 8;
#pragma unroll
    for (int ks = 0; ks < 4; ++ks) qf[ks] = *(const f16x8*)(qrow + ks * 16);
  }

  float lsum = 0.f;
#pragma unroll
  for (int zz = 0; zz < 4; ++zz) lsum += lsums[(size_t)(zz * 16 + bh) * 2048 + qw];
  const float inv = 1.0f / lsum;

  f32x16 oacc[2];
  oacc[0] = zero16();
  oacc[1] = zero16();
  char* trw = smem + 16384 + (w << 12);  // per-wave [32 q][32 k] f32, swz k^q
  const _Float16* vbase = vt + (size_t)((b * 8 + h) * 64) * 2048;

  const int kb0 = z * 8;
  stage_k64(smem, kr, b, h, kb0, tid);
  __syncthreads();

  for (int t = 0; t < 8; ++t) {
    const int cur = t & 1, kb = kb0 + t;
    if (t < 7) stage_k64(smem + (cur ^ 1) * 8192, kr, b, h, kb + 1, tid);
    // prefetch V A-fragments for this tile (consumed after the S phase)
    f16x8 vp[8];
#pragma unroll
    for (int f = 0; f < 8; ++f) {
      int ks4 = f >> 2, kb2 = (f >> 1) & 1, dt = f & 1;
      int d = dt * 32 + lo;
      vp[f] = *(const f16x8*)(vbase + (size_t)d * 2048 + kb * 64 + ks4 * 32 + kb2 * 16 + hi * 8);
    }
    char* kbuf = smem + cur * 8192;
#pragma unroll
    for (int ks4 = 0; ks4 < 2; ++ks4) {
      f32x16 acc = zero16();
      int krw = ks4 * 32 + lo;
#pragma unroll
      for (int ks = 0; ks < 4; ++ks) {
        f16x8 kf = *(const f16x8*)(kbuf + ((krw * 128 + ks * 32 + hi * 16) ^ ((krw & 7) << 4)));
        acc = __builtin_amdgcn_mfma_f32_32x32x16_f16(kf, qf[ks], acc, 0, 0, 0);
      }
      float p[16];
      if (!mflag) {
#pragma unroll
        for (int r = 0; r < 16; ++r) p[r] = exp2f(acc[r] * C) * inv;
      } else {
#pragma unroll
        for (int r = 0; r < 16; ++r) {
          int kg = kb * 64 + ks4 * 32 + (r & 3) + 8 * ((r >> 2) & 3) + 4 * hi;
          float mv = mask[(size_t)(b * 2048 + qw) * 2048 + kg];
          p[r] = exp2f((acc[r] - 1e9f * mv) * C) * inv;
        }
      }
      // transpose via LDS: element (q,k) at q*128 + ((k^q)&31)*4
#pragma unroll
      for (int r = 0; r < 16; ++r) {
        int krow = (r & 3) + 8 * ((r >> 2) & 3) + 4 * hi;
        *(float*)(trw + lo * 128 + (((krow ^ lo) & 31) << 2)) = p[r];
      }
      // read back float4 (component-permuted by q&3), coalesced stores
      float* srow = scores + (size_t)(bh * 2048 + q0 + w * 32) * 2048 + kb * 64 + ks4 * 32;
      {
        int qrd = l >> 3, m4 = (l & 7) << 2;
#pragma unroll
        for (int j = 0; j < 4; ++j) {
          int q = qrd + 8 * j;
          int g = (m4 ^ (q & 28)) & 31;
          float4 v = *(const float4*)(trw + q * 128 + g * 4);
          const float* vf = (const float*)&v;
          int px = q & 3;
          float4 o;
          o.x = vf[0 ^ px]; o.y = vf[1 ^ px]; o.z = vf[2 ^ px]; o.w = vf[3 ^ px];
          *(float4*)(srow + (size_t)q * 2048 + m4) = o;
        }
      }
      // PV: build P^T fragments in-register, A = prefetched V fragments
#pragma unroll
      for (int kb2 = 0; kb2 < 2; ++kb2) {
        unsigned X0 = pkh(p[8 * kb2 + 0], p[8 * kb2 + 1]);
        unsigned X1 = pkh(p[8 * kb2 + 2], p[8 * kb2 + 3]);
        unsigned Y0 = pkh(p[8 * kb2 + 4], p[8 * kb2 + 5]);
        unsigned Y1 = pkh(p[8 * kb2 + 6], p[8 * kb2 + 7]);
        unsigned w0, w1, w2, w3;
        swap32(X0, Y0, hi, w0, w2);
        swap32(X1, Y1, hi, w1, w3);
        union { unsigned u[4]; f16x8 v; } pf;
        pf.u[0] = w0; pf.u[1] = w1; pf.u[2] = w2; pf.u[3] = w3;
#pragma unroll
        for (int dt = 0; dt < 2; ++dt)
          oacc[dt] = __builtin_amdgcn_mfma_f32_32x32x16_f16(vp[ks4 * 4 + kb2 * 2 + dt],
                                                            pf.v, oacc[dt], 0, 0, 0);
      }
    }
    __syncthreads();
  }
  // partial PV out (f32): opart[z][b*2048+qw][h*64+d]
  float* orow = opart + (size_t)z * 4096 * 512 + (size_t)(b * 2048 + qw) * 512 + h * 64;
#pragma unroll
  for (int dt = 0; dt < 2; ++dt)
#pragma unroll
    for (int a = 0; a < 4; ++a) {
      int d = dt * 32 + 8 * a + 4 * hi;
      float4 o;
      o.x = oacc[dt][4 * a + 0]; o.y = oacc[dt][4 * a + 1];
      o.z = oacc[dt][4 * a + 2]; o.w = oacc[dt][4 * a + 3];
      *(float4*)(orow + d) = o;
    }
}

// ---------------------------------------------------------------------------
extern "C" void kernel_launch(void* const* d_in, const int* in_sizes, int n_in,
                              void* d_out, int out_size, void* d_ws, size_t ws_size,
                              hipStream_t stream) {
  const float* querys = (const float*)d_in[0];
  const float* keys   = (const float*)d_in[1];
  const float* values = (const float*)d_in[2];
  const float* mask   = (const float*)d_in[3];
  const float* Wq = (const float*)d_in[4];
  const float* Wk = (const float*)d_in[5];
  const float* Wv = (const float*)d_in[6];
  const float* Wo = (const float*)d_in[7];

  char* ws = (char*)d_ws;
  const size_t MB = 1048576;
  _Float16* q_r  = (_Float16*)(ws + 0 * MB);
  _Float16* k_r  = (_Float16*)(ws + 4 * MB);
  _Float16* v_t  = (_Float16*)(ws + 8 * MB);
  float*    opart = (float*)(ws + 12 * MB);   // [4][4096][512] f32 = 32MB
  float*    lsums = (float*)(ws + 44 * MB);   // [4][16][2048] f32 = 512KB
  int*      flag  = (int*)(ws + 45 * MB);

  float* out_sc = (float*)d_out + (size_t)4096 * 512;

  hipMemsetAsync(flag, 0, 4, stream);
  mask_scan<<<dim3(1024), 256, 0, stream>>>(mask, flag);

  proj_kernel<<<dim3(4, 64, 3), 256, 0, stream>>>(querys, keys, values, Wq, Wk, Wv,
                                                  q_r, k_r, v_t);

  lsum_kernel<<<dim3(32, 16, 4), 128, 0, stream>>>(q_r, k_r, mask, flag, lsums);

  attn_kernel<<<dim3(32, 16, 4), 128, 0, stream>>>(q_r, k_r, v_t, mask, flag, lsums,
                                                   out_sc, opart);

  out_gemm<<<dim3(4, 64), 256, 0, stream>>>(opart, Wo, (float*)d_out);
}